// Round 2
// baseline (912.304 us; speedup 1.0000x reference)
//
#include <hip/hip_runtime.h>
#include <math.h>

#define BB 32
#define NN 1000
#define CC 128
#define FF 128
#define OO 64
#define CAP 128
#define NB 40

// exact replica of JAX's np.float32(1.0 - 0.8) = 0.20000000298023224f
#define RMC ((float)(1.0 - 0.8))

// ---------------- init: copy mask, n_cur, |p| norms, gate=1 ----------------
__global__ void k_init(const float* __restrict__ mask, const int* __restrict__ Nn,
                       const float* __restrict__ p0, const float* __restrict__ p1,
                       float* __restrict__ m, int* __restrict__ ncur,
                       float* __restrict__ pn, float* __restrict__ gate){
  int tid = threadIdx.x;
  for (int i = tid; i < BB*NN; i += 256){ m[i] = mask[i]; gate[i] = 1.0f; }
  if (tid < BB) ncur[tid] = Nn[tid];
  if (tid == 64){ float s=0.f; for(int c=0;c<FF;c++) s += p0[c]*p0[c]; pn[0] = sqrtf(s); }
  if (tid == 65){ float s=0.f; for(int c=0;c<FF;c++) s += p1[c]*p1[c]; pn[1] = sqrtf(s); }
}

// ---------------- transpose the three W's: Wt[s][c][f] = W[s][f][c] ----------------
__global__ void k_wt(const float* __restrict__ W0, const float* __restrict__ W1,
                     const float* __restrict__ W2, float* __restrict__ Wt){
  int s = blockIdx.x;
  const float* W = (s == 0) ? W0 : (s == 1) ? W1 : W2;
  float* T = Wt + (size_t)s*FF*CC;
  for (int e = threadIdx.x; e < FF*CC; e += 256){
    int c = e >> 7, f = e & 127;
    T[e] = W[f*CC + c];
  }
}

// ---------------- CSR build (A is 0/1, symmetric, pre-masked), float4 scan ----------------
__global__ void k_csr(const float* __restrict__ A, short* __restrict__ idx,
                      int* __restrict__ cnt){
  int i = blockIdx.x, b = blockIdx.y, lane = threadIdx.x;   // block = 64 (one wave)
  const float4* row = (const float4*)(A + ((size_t)b*NN + i)*NN);
  short* out = idx + ((size_t)b*NN + i)*CAP;
  int count = 0;
  for (int base = 0; base < 250; base += 64){               // 1000 = 250 float4
    int q = base + lane;
    float4 v;
    if (q < 250) v = row[q]; else { v.x=v.y=v.z=v.w=0.f; }
    int lc = (v.x!=0.f) + (v.y!=0.f) + (v.z!=0.f) + (v.w!=0.f);
    int pre = lc;
    #pragma unroll
    for (int off = 1; off < 64; off <<= 1){
      int t = __shfl_up(pre, off);
      if (lane >= off) pre += t;
    }
    int tot = __shfl(pre, 63);
    pre -= lc;                                              // exclusive prefix
    int slot = count + pre;
    int j = q*4;
    if (v.x!=0.f && slot < CAP) out[slot++] = (short)j;
    if (v.y!=0.f && slot < CAP) out[slot++] = (short)(j+1);
    if (v.z!=0.f && slot < CAP) out[slot++] = (short)(j+2);
    if (v.w!=0.f && slot < CAP) out[slot++] = (short)(j+3);
    count += tot;
  }
  if (lane == 0) cnt[b*NN + i] = (count < CAP) ? count : CAP;
}

// ---------------- degree -> D = (1 + sum_nbr m_j + 1e-5)^-1/2 ----------------
__global__ void k_deg(const short* __restrict__ idx, const int* __restrict__ cnt,
                      const float* __restrict__ m, float* __restrict__ D){
  __shared__ float ml[NN];
  int b = blockIdx.x, tid = threadIdx.x;
  for (int i = tid; i < NN; i += 256) ml[i] = m[b*NN + i];
  __syncthreads();
  for (int j = tid; j < NN; j += 256){
    const short* r = idx + ((size_t)b*NN + j)*CAP;
    int c = cnt[b*NN + j];
    float s = 0.f;
    for (int k = 0; k < c; k++) s += ml[r[k]];
    D[b*NN + j] = 1.0f / sqrtf(s + 1.0f + 1e-5f);
  }
}

// ---------------- Y_i = sum_{j in nbr(i)} D_j * gate_j * h_j  (gate folded) ----------------
__global__ void k_agg(const short* __restrict__ idx, const int* __restrict__ cnt,
                      const float* __restrict__ D, const float* __restrict__ gate,
                      const float* __restrict__ h, float* __restrict__ Y){
  __shared__ short nb[CAP];
  __shared__ float dn[CAP];
  int blk = blockIdx.x;                    // XCD swizzle: same b lands on same XCD
  int b = (blk & 7) + 8*((blk >> 3) & 3);
  int i = blk >> 5;
  int c = threadIdx.x;                     // block = 128
  int n = cnt[b*NN + i];
  const short* r = idx + ((size_t)b*NN + i)*CAP;
  for (int k = c; k < n; k += 128){
    int j = r[k];
    nb[k] = (short)j;
    dn[k] = D[b*NN + j] * gate[b*NN + j];
  }
  __syncthreads();
  float acc = 0.f;
  const float* hb = h + (size_t)b*NN*CC;
  for (int k = 0; k < n; k++) acc += dn[k]*hb[(size_t)nb[k]*CC + c];
  Y[((size_t)b*NN + i)*CC + c] = acc;
}

// ---- t = D*(m*Y) + D^2*(gate*h) ; H = relu(t @ W^T + b) * m ; register-tiled ----
__global__ void k_lin(const float* __restrict__ Y, const float* __restrict__ h,
                      const float* __restrict__ Dv, const float* __restrict__ m,
                      const float* __restrict__ gate,
                      const float* __restrict__ Wt,   // [cc][f] transposed
                      const float* __restrict__ bias, float* __restrict__ Hout){
  __shared__ float t[NB][CC];              // 20.5 KB
  int b = blockIdx.y, tid = threadIdx.x;   // block = 256
  int i0 = blockIdx.x * NB;
  for (int e = tid; e < NB*CC; e += 256){
    int n = e >> 7, c = e & 127;
    int i = i0 + n;
    float Di = Dv[b*NN + i], mi = m[b*NN + i], gi = gate[b*NN + i];
    size_t o = ((size_t)b*NN + i)*CC + c;
    t[n][c] = Di*(mi*Y[o]) + Di*Di*(gi*h[o]);
  }
  __syncthreads();
  int fg = tid & 31;                       // 4 consecutive f per thread
  int nr = tid >> 5;                       // 0..7 node-row
  float acc[5][4];
  float4 bi = ((const float4*)bias)[fg];
  #pragma unroll
  for (int n5 = 0; n5 < 5; n5++){
    acc[n5][0]=bi.x; acc[n5][1]=bi.y; acc[n5][2]=bi.z; acc[n5][3]=bi.w;
  }
  for (int c4 = 0; c4 < 32; c4++){
    float4 tv[5];
    #pragma unroll
    for (int n5 = 0; n5 < 5; n5++)
      tv[n5] = *((const float4*)&t[nr + n5*8][c4*4]);
    #pragma unroll
    for (int k = 0; k < 4; k++){
      float4 wv = ((const float4*)Wt)[(size_t)(c4*4 + k)*32 + fg];
      #pragma unroll
      for (int n5 = 0; n5 < 5; n5++){
        float tvv = (k==0) ? tv[n5].x : (k==1) ? tv[n5].y : (k==2) ? tv[n5].z : tv[n5].w;
        acc[n5][0] += tvv*wv.x; acc[n5][1] += tvv*wv.y;
        acc[n5][2] += tvv*wv.z; acc[n5][3] += tvv*wv.w;
      }
    }
  }
  #pragma unroll
  for (int n5 = 0; n5 < 5; n5++){
    int i = i0 + nr + n5*8;
    float mi = m[b*NN + i];
    float4 o4;
    o4.x = fmaxf(acc[n5][0], 0.f)*mi;
    o4.y = fmaxf(acc[n5][1], 0.f)*mi;
    o4.z = fmaxf(acc[n5][2], 0.f)*mi;
    o4.w = fmaxf(acc[n5][3], 0.f)*mi;
    ((float4*)&Hout[((size_t)b*NN + i)*CC])[fg] = o4;
  }
}

// ---------------- pool scores y_i = (H_i . p) / |p| ----------------
__global__ void k_score(const float* __restrict__ H, const float* __restrict__ p,
                        const float* __restrict__ pn, float* __restrict__ y){
  int i = blockIdx.x, b = blockIdx.y, lane = threadIdx.x;  // block = 64
  const float* hrow = H + ((size_t)b*NN + i)*CC;
  float s = hrow[lane]*p[lane] + hrow[lane+64]*p[lane+64];
  for (int off = 32; off > 0; off >>= 1) s += __shfl_down(s, off);
  if (lane == 0) y[b*NN + i] = s / pn[0];
}

// ---------------- top-k pool: stable ranks, new mask, gate ----------------
__global__ void k_pool(const float* __restrict__ y, float* __restrict__ m,
                       int* __restrict__ ncur, float* __restrict__ gate){
  __shared__ float yk[NN];
  __shared__ float yl[NN];
  int b = blockIdx.x, tid = threadIdx.x;   // block = 256
  int n = ncur[b];
  for (int i = tid; i < NN; i += 256){
    float v = y[b*NN + i];
    yl[i] = v;
    yk[i] = (m[b*NN + i] > 0.f) ? v : INFINITY;
  }
  __syncthreads();
  int nr = (int)((float)n * RMC);
  float myv[4]; int cnt4[4];
  #pragma unroll
  for (int r = 0; r < 4; r++){
    int i = tid + r*256;
    myv[r] = (i < NN) ? yk[i] : INFINITY;
    cnt4[r] = 0;
  }
  for (int j = 0; j < NN; j++){
    float yj = yk[j];
    #pragma unroll
    for (int r = 0; r < 4; r++)
      cnt4[r] += (int)((yj < myv[r]) || (yj == myv[r] && j < tid + r*256));
  }
  #pragma unroll
  for (int r = 0; r < 4; r++){
    int i = tid + r*256;
    if (i < NN){
      bool keep = (cnt4[r] >= nr) && (m[b*NN + i] > 0.f);
      m[b*NN + i]    = keep ? 1.0f : 0.0f;
      gate[b*NN + i] = keep ? tanhf(yl[i]) : 0.0f;
    }
  }
  if (tid == 0) ncur[b] = n - nr;
}

// ---------------- global max pool + FC ----------------
__global__ void k_final(const float* __restrict__ H, const float* __restrict__ Wfc,
                        const float* __restrict__ bfc, float* __restrict__ out){
  __shared__ float red[4][FF];
  __shared__ float g[FF];
  int b = blockIdx.x, tid = threadIdx.x;   // block = 512
  int sub = tid >> 7, c = tid & 127;
  float mx = -INFINITY;
  for (int i = sub; i < NN; i += 4) mx = fmaxf(mx, H[((size_t)b*NN + i)*CC + c]);
  red[sub][c] = mx;
  __syncthreads();
  if (tid < FF) g[tid] = fmaxf(fmaxf(red[0][tid], red[1][tid]),
                               fmaxf(red[2][tid], red[3][tid]));
  __syncthreads();
  if (tid < OO){
    float acc = bfc[tid];
    for (int c2 = 0; c2 < FF; c2++) acc += g[c2]*Wfc[tid*FF + c2];
    out[b*OO + tid] = acc;
  }
}

extern "C" void kernel_launch(void* const* d_in, const int* in_sizes, int n_in,
                              void* d_out, int out_size, void* d_ws, size_t ws_size,
                              hipStream_t stream) {
  const float* x    = (const float*)d_in[0];
  const float* A    = (const float*)d_in[1];
  const float* mask = (const float*)d_in[2];
  const int*   Nn   = (const int*)  d_in[3];
  const float* W0   = (const float*)d_in[4];
  const float* b0   = (const float*)d_in[5];
  const float* W1   = (const float*)d_in[6];
  const float* b1   = (const float*)d_in[7];
  const float* W2   = (const float*)d_in[8];
  const float* b2   = (const float*)d_in[9];
  const float* p0   = (const float*)d_in[10];
  const float* p1   = (const float*)d_in[11];
  const float* Wfc  = (const float*)d_in[12];
  const float* bfc  = (const float*)d_in[13];
  float* out = (float*)d_out;

  // workspace carve (~41.7 MB)
  char* w = (char*)d_ws;
  float* H   = (float*)w; w += (size_t)BB*NN*CC*4;      // 16.38 MB
  float* Yb  = (float*)w; w += (size_t)BB*NN*CC*4;      // 16.38 MB
  short* idx = (short*)w; w += (size_t)BB*NN*CAP*2;     // 8.19 MB
  float* Wt  = (float*)w; w += (size_t)3*FF*CC*4;       // 192 KB
  int*   cnt = (int*)w;   w += (size_t)BB*NN*4;
  float* D   = (float*)w; w += (size_t)BB*NN*4;
  float* m   = (float*)w; w += (size_t)BB*NN*4;
  float* ysc = (float*)w; w += (size_t)BB*NN*4;
  float* gate= (float*)w; w += (size_t)BB*NN*4;
  int*   ncur= (int*)w;   w += 128;                     // 32 ints (fixed: was 64B)
  float* pn  = (float*)w; w += 64;

  dim3 gNB(NN, BB);

  k_init<<<1, 256, 0, stream>>>(mask, Nn, p0, p1, m, ncur, pn, gate);
  k_wt<<<3, 256, 0, stream>>>(W0, W1, W2, Wt);
  k_csr<<<gNB, 64, 0, stream>>>(A, idx, cnt);

  // ---- stage 1 (h = x, gate = 1) ----
  k_deg<<<BB, 256, 0, stream>>>(idx, cnt, m, D);
  k_agg<<<BB*NN, 128, 0, stream>>>(idx, cnt, D, gate, x, Yb);
  k_lin<<<dim3(25, BB), 256, 0, stream>>>(Yb, x, D, m, gate, Wt + 0*FF*CC, b0, H);
  k_score<<<gNB, 64, 0, stream>>>(H, p0, pn + 0, ysc);
  k_pool<<<BB, 256, 0, stream>>>(ysc, m, ncur, gate);

  // ---- stage 2 (gate-1 folded into agg/lin) ----
  k_deg<<<BB, 256, 0, stream>>>(idx, cnt, m, D);
  k_agg<<<BB*NN, 128, 0, stream>>>(idx, cnt, D, gate, H, Yb);
  k_lin<<<dim3(25, BB), 256, 0, stream>>>(Yb, H, D, m, gate, Wt + 1*FF*CC, b1, H);
  k_score<<<gNB, 64, 0, stream>>>(H, p1, pn + 1, ysc);
  k_pool<<<BB, 256, 0, stream>>>(ysc, m, ncur, gate);

  // ---- stage 3 ----
  k_deg<<<BB, 256, 0, stream>>>(idx, cnt, m, D);
  k_agg<<<BB*NN, 128, 0, stream>>>(idx, cnt, D, gate, H, Yb);
  k_lin<<<dim3(25, BB), 256, 0, stream>>>(Yb, H, D, m, gate, Wt + 2*FF*CC, b2, H);

  // ---- global max pool + FC ----
  k_final<<<BB, 512, 0, stream>>>(H, Wfc, bfc, out);
}

// Round 3
// 570.057 us; speedup vs baseline: 1.6004x; 1.6004x over previous
//
#include <hip/hip_runtime.h>
#include <math.h>

#define BB 32
#define NN 1000
#define CC 128
#define FF 128
#define OO 64
#define CAP 128
#define NB 40

// exact replica of JAX's np.float32(1.0 - 0.8) = 0.20000000298023224f
#define RMC ((float)(1.0 - 0.8))

// ---------------- init: copy mask, n_cur, |p| norms, gate=1 ----------------
__global__ void k_init(const float* __restrict__ mask, const int* __restrict__ Nn,
                       const float* __restrict__ p0, const float* __restrict__ p1,
                       float* __restrict__ m, int* __restrict__ ncur0,
                       float* __restrict__ pn, float* __restrict__ gate){
  int tid = threadIdx.x;
  for (int i = tid; i < BB*NN; i += 256){ m[i] = mask[i]; gate[i] = 1.0f; }
  if (tid < BB) ncur0[tid] = Nn[tid];
  if (tid == 64){ float s=0.f; for(int c=0;c<FF;c++) s += p0[c]*p0[c]; pn[0] = sqrtf(s); }
  if (tid == 65){ float s=0.f; for(int c=0;c<FF;c++) s += p1[c]*p1[c]; pn[1] = sqrtf(s); }
}

// ---------------- transpose the three W's: Wt[s][c][f] = W[s][f][c] ----------------
__global__ void k_wt(const float* __restrict__ W0, const float* __restrict__ W1,
                     const float* __restrict__ W2, float* __restrict__ Wt){
  int s = blockIdx.x;
  const float* W = (s == 0) ? W0 : (s == 1) ? W1 : W2;
  float* T = Wt + (size_t)s*FF*CC;
  for (int e = threadIdx.x; e < FF*CC; e += 256){
    int c = e >> 7, f = e & 127;
    T[e] = W[f*CC + c];
  }
}

// ---------------- CSR build (A is 0/1, symmetric, pre-masked), float4 scan ----------------
__global__ void k_csr(const float* __restrict__ A, short* __restrict__ idx,
                      int* __restrict__ cnt){
  int i = blockIdx.x, b = blockIdx.y, lane = threadIdx.x;   // block = 64 (one wave)
  const float4* row = (const float4*)(A + ((size_t)b*NN + i)*NN);
  short* out = idx + ((size_t)b*NN + i)*CAP;
  int count = 0;
  for (int base = 0; base < 250; base += 64){               // 1000 = 250 float4
    int q = base + lane;
    float4 v;
    if (q < 250) v = row[q]; else { v.x=v.y=v.z=v.w=0.f; }
    int lc = (v.x!=0.f) + (v.y!=0.f) + (v.z!=0.f) + (v.w!=0.f);
    int pre = lc;
    #pragma unroll
    for (int off = 1; off < 64; off <<= 1){
      int t = __shfl_up(pre, off);
      if (lane >= off) pre += t;
    }
    int tot = __shfl(pre, 63);
    pre -= lc;                                              // exclusive prefix
    int slot = count + pre;
    int j = q*4;
    if (v.x!=0.f && slot < CAP) out[slot++] = (short)j;
    if (v.y!=0.f && slot < CAP) out[slot++] = (short)(j+1);
    if (v.z!=0.f && slot < CAP) out[slot++] = (short)(j+2);
    if (v.w!=0.f && slot < CAP) out[slot++] = (short)(j+3);
    count += tot;
  }
  if (lane == 0) cnt[b*NN + i] = (count < CAP) ? count : CAP;
}

// ---------------- degree -> D = (1 + sum_nbr m_j + 1e-5)^-1/2 ----------------
__global__ void k_deg(const short* __restrict__ idx, const int* __restrict__ cnt,
                      const float* __restrict__ m, float* __restrict__ D){
  __shared__ float ml[NN];
  int b = blockIdx.x, tid = threadIdx.x;
  for (int i = tid; i < NN; i += 256) ml[i] = m[b*NN + i];
  __syncthreads();
  for (int j = tid; j < NN; j += 256){
    const short* r = idx + ((size_t)b*NN + j)*CAP;
    int c = cnt[b*NN + j];
    float s = 0.f;
    for (int k = 0; k < c; k++) s += ml[r[k]];
    D[b*NN + j] = 1.0f / sqrtf(s + 1.0f + 1e-5f);
  }
}

// ---------------- Y_i = sum_{j in nbr(i)} D_j * gate_j * h_j  (gate folded) ----------------
__global__ void k_agg(const short* __restrict__ idx, const int* __restrict__ cnt,
                      const float* __restrict__ D, const float* __restrict__ gate,
                      const float* __restrict__ h, float* __restrict__ Y){
  __shared__ short nb[CAP];
  __shared__ float dn[CAP];
  int blk = blockIdx.x;                    // XCD swizzle: same b lands on same XCD
  int b = (blk & 7) + 8*((blk >> 3) & 3);
  int i = blk >> 5;
  int c = threadIdx.x;                     // block = 128
  int n = cnt[b*NN + i];
  const short* r = idx + ((size_t)b*NN + i)*CAP;
  for (int k = c; k < n; k += 128){
    int j = r[k];
    nb[k] = (short)j;
    dn[k] = D[b*NN + j] * gate[b*NN + j];
  }
  __syncthreads();
  float acc = 0.f;
  const float* hb = h + (size_t)b*NN*CC;
  for (int k = 0; k < n; k++) acc += dn[k]*hb[(size_t)nb[k]*CC + c];
  Y[((size_t)b*NN + i)*CC + c] = acc;
}

// ---- t = D*(m*Y) + D^2*(gate*h) ; H = relu(t @ W^T + b) * m ; register-tiled ----
__global__ void k_lin(const float* __restrict__ Y, const float* __restrict__ h,
                      const float* __restrict__ Dv, const float* __restrict__ m,
                      const float* __restrict__ gate,
                      const float* __restrict__ Wt,   // [cc][f] transposed
                      const float* __restrict__ bias, float* __restrict__ Hout){
  __shared__ float t[NB][CC];              // 20.5 KB
  int b = blockIdx.y, tid = threadIdx.x;   // block = 256
  int i0 = blockIdx.x * NB;
  for (int e = tid; e < NB*CC; e += 256){
    int n = e >> 7, c = e & 127;
    int i = i0 + n;
    float Di = Dv[b*NN + i], mi = m[b*NN + i], gi = gate[b*NN + i];
    size_t o = ((size_t)b*NN + i)*CC + c;
    t[n][c] = Di*(mi*Y[o]) + Di*Di*(gi*h[o]);
  }
  __syncthreads();
  int fg = tid & 31;                       // 4 consecutive f per thread
  int nr = tid >> 5;                       // 0..7 node-row
  float acc[5][4];
  float4 bi = ((const float4*)bias)[fg];
  #pragma unroll
  for (int n5 = 0; n5 < 5; n5++){
    acc[n5][0]=bi.x; acc[n5][1]=bi.y; acc[n5][2]=bi.z; acc[n5][3]=bi.w;
  }
  for (int c4 = 0; c4 < 32; c4++){
    float4 tv[5];
    #pragma unroll
    for (int n5 = 0; n5 < 5; n5++)
      tv[n5] = *((const float4*)&t[nr + n5*8][c4*4]);
    #pragma unroll
    for (int k = 0; k < 4; k++){
      float4 wv = ((const float4*)Wt)[(size_t)(c4*4 + k)*32 + fg];
      #pragma unroll
      for (int n5 = 0; n5 < 5; n5++){
        float tvv = (k==0) ? tv[n5].x : (k==1) ? tv[n5].y : (k==2) ? tv[n5].z : tv[n5].w;
        acc[n5][0] += tvv*wv.x; acc[n5][1] += tvv*wv.y;
        acc[n5][2] += tvv*wv.z; acc[n5][3] += tvv*wv.w;
      }
    }
  }
  #pragma unroll
  for (int n5 = 0; n5 < 5; n5++){
    int i = i0 + nr + n5*8;
    float mi = m[b*NN + i];
    float4 o4;
    o4.x = fmaxf(acc[n5][0], 0.f)*mi;
    o4.y = fmaxf(acc[n5][1], 0.f)*mi;
    o4.z = fmaxf(acc[n5][2], 0.f)*mi;
    o4.w = fmaxf(acc[n5][3], 0.f)*mi;
    ((float4*)&Hout[((size_t)b*NN + i)*CC])[fg] = o4;
  }
}

// ---------------- pool scores y_i = (H_i . p) / |p| ----------------
__global__ void k_score(const float* __restrict__ H, const float* __restrict__ p,
                        const float* __restrict__ pn, float* __restrict__ y){
  int i = blockIdx.x, b = blockIdx.y, lane = threadIdx.x;  // block = 64
  const float* hrow = H + ((size_t)b*NN + i)*CC;
  float s = hrow[lane]*p[lane] + hrow[lane+64]*p[lane+64];
  for (int off = 32; off > 0; off >>= 1) s += __shfl_down(s, off);
  if (lane == 0) y[b*NN + i] = s / pn[0];
}

// ---------------- top-k pool: 1 node/thread, float4 LDS scan, ping-pong ncur ----------------
__global__ void k_pool(const float* __restrict__ y, float* __restrict__ m,
                       const int* __restrict__ ncur_in, int* __restrict__ ncur_out,
                       float* __restrict__ gate){
  __shared__ float yk[NN];
  int b = blockIdx.y, tid = threadIdx.x;   // grid (4, BB), block = 256
  int i = blockIdx.x*256 + tid;
  for (int j = tid; j < NN; j += 256)
    yk[j] = (m[b*NN + j] > 0.f) ? y[b*NN + j] : INFINITY;
  __syncthreads();
  int n = ncur_in[b];
  int nr = (int)((float)n * RMC);          // exact JAX semantics (f32 mult, trunc)
  float myv = (i < NN) ? yk[i] : INFINITY;
  int cnt = 0;
  const float4* yk4 = (const float4*)yk;   // broadcast reads: conflict-free
  #pragma unroll 5
  for (int q = 0; q < 250; q++){
    float4 v = yk4[q];
    int j0 = q*4;
    cnt += (int)((v.x < myv) || (v.x == myv && j0     < i));
    cnt += (int)((v.y < myv) || (v.y == myv && j0 + 1 < i));
    cnt += (int)((v.z < myv) || (v.z == myv && j0 + 2 < i));
    cnt += (int)((v.w < myv) || (v.w == myv && j0 + 3 < i));
  }
  if (i < NN){
    bool keep = (cnt >= nr) && (m[b*NN + i] > 0.f);
    m[b*NN + i]    = keep ? 1.0f : 0.0f;
    gate[b*NN + i] = keep ? tanhf(y[b*NN + i]) : 0.0f;
  }
  if (blockIdx.x == 0 && tid == 0) ncur_out[b] = n - nr;
}

// ---------------- global max pool + FC ----------------
__global__ void k_final(const float* __restrict__ H, const float* __restrict__ Wfc,
                        const float* __restrict__ bfc, float* __restrict__ out){
  __shared__ float red[4][FF];
  __shared__ float g[FF];
  int b = blockIdx.x, tid = threadIdx.x;   // block = 512
  int sub = tid >> 7, c = tid & 127;
  float mx = -INFINITY;
  for (int i = sub; i < NN; i += 4) mx = fmaxf(mx, H[((size_t)b*NN + i)*CC + c]);
  red[sub][c] = mx;
  __syncthreads();
  if (tid < FF) g[tid] = fmaxf(fmaxf(red[0][tid], red[1][tid]),
                               fmaxf(red[2][tid], red[3][tid]));
  __syncthreads();
  if (tid < OO){
    float acc = bfc[tid];
    for (int c2 = 0; c2 < FF; c2++) acc += g[c2]*Wfc[tid*FF + c2];
    out[b*OO + tid] = acc;
  }
}

extern "C" void kernel_launch(void* const* d_in, const int* in_sizes, int n_in,
                              void* d_out, int out_size, void* d_ws, size_t ws_size,
                              hipStream_t stream) {
  const float* x    = (const float*)d_in[0];
  const float* A    = (const float*)d_in[1];
  const float* mask = (const float*)d_in[2];
  const int*   Nn   = (const int*)  d_in[3];
  const float* W0   = (const float*)d_in[4];
  const float* b0   = (const float*)d_in[5];
  const float* W1   = (const float*)d_in[6];
  const float* b1   = (const float*)d_in[7];
  const float* W2   = (const float*)d_in[8];
  const float* b2   = (const float*)d_in[9];
  const float* p0   = (const float*)d_in[10];
  const float* p1   = (const float*)d_in[11];
  const float* Wfc  = (const float*)d_in[12];
  const float* bfc  = (const float*)d_in[13];
  float* out = (float*)d_out;

  // workspace carve (~41.7 MB)
  char* w = (char*)d_ws;
  float* H   = (float*)w; w += (size_t)BB*NN*CC*4;      // 16.38 MB
  float* Yb  = (float*)w; w += (size_t)BB*NN*CC*4;      // 16.38 MB
  short* idx = (short*)w; w += (size_t)BB*NN*CAP*2;     // 8.19 MB
  float* Wt  = (float*)w; w += (size_t)3*FF*CC*4;       // 192 KB
  int*   cnt = (int*)w;   w += (size_t)BB*NN*4;
  float* D   = (float*)w; w += (size_t)BB*NN*4;
  float* m   = (float*)w; w += (size_t)BB*NN*4;
  float* ysc = (float*)w; w += (size_t)BB*NN*4;
  float* gate= (float*)w; w += (size_t)BB*NN*4;
  int*   ncur= (int*)w;   w += 3*BB*sizeof(int);        // ping-pong slots
  float* pn  = (float*)w; w += 64;

  dim3 gNB(NN, BB);

  k_init<<<1, 256, 0, stream>>>(mask, Nn, p0, p1, m, ncur, pn, gate);
  k_wt<<<3, 256, 0, stream>>>(W0, W1, W2, Wt);
  k_csr<<<gNB, 64, 0, stream>>>(A, idx, cnt);

  // ---- stage 1 (h = x, gate = 1) ----
  k_deg<<<BB, 256, 0, stream>>>(idx, cnt, m, D);
  k_agg<<<BB*NN, 128, 0, stream>>>(idx, cnt, D, gate, x, Yb);
  k_lin<<<dim3(25, BB), 256, 0, stream>>>(Yb, x, D, m, gate, Wt + 0*FF*CC, b0, H);
  k_score<<<gNB, 64, 0, stream>>>(H, p0, pn + 0, ysc);
  k_pool<<<dim3(4, BB), 256, 0, stream>>>(ysc, m, ncur + 0*BB, ncur + 1*BB, gate);

  // ---- stage 2 (gate-1 folded into agg/lin) ----
  k_deg<<<BB, 256, 0, stream>>>(idx, cnt, m, D);
  k_agg<<<BB*NN, 128, 0, stream>>>(idx, cnt, D, gate, H, Yb);
  k_lin<<<dim3(25, BB), 256, 0, stream>>>(Yb, H, D, m, gate, Wt + 1*FF*CC, b1, H);
  k_score<<<gNB, 64, 0, stream>>>(H, p1, pn + 1, ysc);
  k_pool<<<dim3(4, BB), 256, 0, stream>>>(ysc, m, ncur + 1*BB, ncur + 2*BB, gate);

  // ---- stage 3 ----
  k_deg<<<BB, 256, 0, stream>>>(idx, cnt, m, D);
  k_agg<<<BB*NN, 128, 0, stream>>>(idx, cnt, D, gate, H, Yb);
  k_lin<<<dim3(25, BB), 256, 0, stream>>>(Yb, H, D, m, gate, Wt + 2*FF*CC, b2, H);

  // ---- global max pool + FC ----
  k_final<<<BB, 512, 0, stream>>>(H, Wfc, bfc, out);
}